// Round 2
// baseline (3691.520 us; speedup 1.0000x reference)
//
#include <hip/hip_runtime.h>

#define NB 8
#define NF 16384
#define NE 32768
#define DD 128

static constexpr int ME = NB * NE;  // 262144 edges
static constexpr int MF = NB * NF;  // 131072 faces

typedef short bf16x8 __attribute__((ext_vector_type(8)));
typedef float f32x4 __attribute__((ext_vector_type(4)));

#define MFMA16(a, b, c) __builtin_amdgcn_mfma_f32_16x16x32_bf16((a), (b), (c), 0, 0, 0)

static __device__ __forceinline__ unsigned short f2bf(float f) {
  union { float f; unsigned u; } v; v.f = f;
  unsigned r = (v.u + 0x7fffu + ((v.u >> 16) & 1u)) >> 16;
  return (unsigned short)r;
}

// A/B fragment from LDS/row-major buffer: elements j0..3 at k=kb..kb+3, j4..7 at k=kb+16..kb+19
static __device__ __forceinline__ bf16x8 ld_ab(const unsigned short* p) {
  union { unsigned long long q[2]; bf16x8 v; } u;
  u.q[0] = *(const unsigned long long*)(p);
  u.q[1] = *(const unsigned long long*)(p + 16);
  return u.v;
}

static __device__ __forceinline__ float gelu_exact(float x) {
  return 0.5f * x * (1.0f + erff(x * 0.70710678118654752f));
}
static __device__ __forceinline__ float sigmoidf_(float x) {
  return 1.0f / (1.0f + expf(-x));
}

// Pack fp32 weight (K,N) row-major into bf16 MFMA B-fragment order:
// Wf[((nt*KS + ks)*64 + lane)*8 + j], col = nt*16 + (lane&15),
// k = ks*32 + 16*(j>>2) + 4*(lane>>4) + (j&3)   (same k-map as ld_ab)
__global__ void k_pack(const float* __restrict__ W, unsigned short* __restrict__ Wf,
                       int K, int N) {
  int idx = blockIdx.x * 256 + threadIdx.x;
  if (idx >= K * N) return;
  int j = idx & 7;
  int lane = (idx >> 3) & 63;
  int rest = idx >> 9;
  int KS = K >> 5;
  int ks = rest % KS;
  int nt = rest / KS;
  int col = nt * 16 + (lane & 15);
  int kk = ks * 32 + ((j >> 2) << 4) + ((lane >> 4) << 2) + (j & 3);
  Wf[idx] = f2bf(W[kk * N + col]);
}

// ---------------- Edge kernel: 64 edges per block, 4 waves ----------------
__global__ __launch_bounds__(256) void k_edge(
    const float* __restrict__ Efeat, const float* __restrict__ Ffeat,
    const int* __restrict__ e2f, const int* __restrict__ emask,
    const unsigned short* __restrict__ W1f, const float* __restrict__ b1,
    const unsigned short* __restrict__ W2f, const float* __restrict__ b2,
    const unsigned short* __restrict__ Wgf, const float* __restrict__ bg,
    const float* __restrict__ ge, const float* __restrict__ be,
    float* __restrict__ out, float* __restrict__ Fcnt) {
  __shared__ unsigned short Xs[64 * 388];  // [E|F1|F2] bf16, pitch 388
  __shared__ unsigned short Hs[64 * 260];  // GELU hidden bf16, pitch 260
  __shared__ float Ms[64 * 133];           // msg fp32 -> u fp32, pitch 133
  __shared__ float validf[64];
  __shared__ int f1s[64], f2s[64];

  const int t = threadIdx.x;
  const int lane = t & 63;
  const int w = t >> 6;
  const int eg0 = blockIdx.x * 64;

  if (t < 64) {
    const int eg = eg0 + t;
    const int b = eg >> 15;  // / NE
    const int r1 = e2f[2 * eg], r2 = e2f[2 * eg + 1];
    const bool v = (emask[eg] != 0) && (r1 >= 0) && (r2 >= 0);
    int f1 = r1 < 0 ? 0 : (r1 > NF - 1 ? NF - 1 : r1);
    int f2 = r2 < 0 ? 0 : (r2 > NF - 1 ? NF - 1 : r2);
    f1s[t] = b * NF + f1;
    f2s[t] = b * NF + f2;
    validf[t] = v ? 1.0f : 0.0f;
  }
  __syncthreads();

  {  // stage X = [E | F1 | F2] as bf16
    const int row = t >> 2, q = t & 3;
    const int eg = eg0 + row;
    const float* er = Efeat + (size_t)eg * DD;
    const float* f1r = Ffeat + (size_t)f1s[row] * DD;
    const float* f2r = Ffeat + (size_t)f2s[row] * DD;
    unsigned short* xr = Xs + row * 388;
    for (int c = q * 32; c < q * 32 + 32; c += 4) {
      float4 v0 = *(const float4*)(er + c);
      float4 v1 = *(const float4*)(f1r + c);
      float4 v2 = *(const float4*)(f2r + c);
      xr[c + 0] = f2bf(v0.x); xr[c + 1] = f2bf(v0.y);
      xr[c + 2] = f2bf(v0.z); xr[c + 3] = f2bf(v0.w);
      xr[128 + c + 0] = f2bf(v1.x); xr[128 + c + 1] = f2bf(v1.y);
      xr[128 + c + 2] = f2bf(v1.z); xr[128 + c + 3] = f2bf(v1.w);
      xr[256 + c + 0] = f2bf(v2.x); xr[256 + c + 1] = f2bf(v2.y);
      xr[256 + c + 2] = f2bf(v2.z); xr[256 + c + 3] = f2bf(v2.w);
    }
  }
  __syncthreads();

  // GEMM1: (64x384)@(384x256); wave w -> cols [64w,64w+64)
  f32x4 acc[4][4] = {};
  for (int ks = 0; ks < 12; ++ks) {
    const int kb = ks * 32 + ((lane >> 4) << 2);
    bf16x8 a[4];
    for (int r = 0; r < 4; ++r)
      a[r] = ld_ab(Xs + (r * 16 + (lane & 15)) * 388 + kb);
    for (int n = 0; n < 4; ++n) {
      const int nt = (w << 2) + n;
      bf16x8 bfr = *(const bf16x8*)(W1f + (((nt * 12 + ks) << 6) + lane) * 8);
      for (int r = 0; r < 4; ++r) acc[r][n] = MFMA16(a[r], bfr, acc[r][n]);
    }
  }
  for (int n = 0; n < 4; ++n) {  // H = gelu(acc + b1), bf16
    const int col = (w << 6) + (n << 4) + (lane & 15);
    const float bias = b1[col];
    for (int r = 0; r < 4; ++r)
      for (int ri = 0; ri < 4; ++ri) {
        const int rw = r * 16 + ((lane >> 4) << 2) + ri;
        Hs[rw * 260 + col] = f2bf(gelu_exact(acc[r][n][ri] + bias));
      }
  }
  __syncthreads();

  // GEMM2: (64x256)@(256x128); wave w -> cols [32w,32w+32)
  f32x4 acc2[4][2] = {};
  for (int ks = 0; ks < 8; ++ks) {
    const int kb = ks * 32 + ((lane >> 4) << 2);
    bf16x8 a[4];
    for (int r = 0; r < 4; ++r)
      a[r] = ld_ab(Hs + (r * 16 + (lane & 15)) * 260 + kb);
    for (int n = 0; n < 2; ++n) {
      const int nt = (w << 1) + n;
      bf16x8 bfr = *(const bf16x8*)(W2f + (((nt * 8 + ks) << 6) + lane) * 8);
      for (int r = 0; r < 4; ++r) acc2[r][n] = MFMA16(a[r], bfr, acc2[r][n]);
    }
  }
  for (int n = 0; n < 2; ++n) {  // msg = (acc + b2) * valid, fp32 in LDS
    const int col = (w << 5) + (n << 4) + (lane & 15);
    const float bias = b2[col];
    for (int r = 0; r < 4; ++r)
      for (int ri = 0; ri < 4; ++ri) {
        const int rw = r * 16 + ((lane >> 4) << 2) + ri;
        Ms[rw * 133 + col] = (acc2[r][n][ri] + bias) * validf[rw];
      }
  }
  __syncthreads();

  // GEMM3 (gate): [E | msg](64x256)@(256x128)
  f32x4 acc3[4][2] = {};
  for (int ks = 0; ks < 8; ++ks) {
    const int kb = (ks & 3) * 32 + ((lane >> 4) << 2);
    bf16x8 a[4];
    if (ks < 4) {
      for (int r = 0; r < 4; ++r)
        a[r] = ld_ab(Xs + (r * 16 + (lane & 15)) * 388 + kb);
    } else {
      for (int r = 0; r < 4; ++r) {
        const float* p = Ms + (r * 16 + (lane & 15)) * 133 + kb;
        union { unsigned short us[8]; bf16x8 v; } u;
        for (int j = 0; j < 4; ++j) { u.us[j] = f2bf(p[j]); u.us[4 + j] = f2bf(p[16 + j]); }
        a[r] = u.v;
      }
    }
    for (int n = 0; n < 2; ++n) {
      const int nt = (w << 1) + n;
      bf16x8 bfr = *(const bf16x8*)(Wgf + (((nt * 8 + ks) << 6) + lane) * 8);
      for (int r = 0; r < 4; ++r) acc3[r][n] = MFMA16(a[r], bfr, acc3[r][n]);
    }
  }
  __syncthreads();  // all Ms reads done before in-place overwrite

  for (int n = 0; n < 2; ++n) {  // u = E + sigmoid(logit)*msg, in place
    const int col = (w << 5) + (n << 4) + (lane & 15);
    const float bias = bg[col];
    for (int r = 0; r < 4; ++r)
      for (int ri = 0; ri < 4; ++ri) {
        const int rw = r * 16 + ((lane >> 4) << 2) + ri;
        const float gate = sigmoidf_(acc3[r][n][ri] + bias);
        const float msg = Ms[rw * 133 + col];
        const float ev = Efeat[(size_t)(eg0 + rw) * DD + col];
        Ms[rw * 133 + col] = ev + gate * msg;
      }
  }
  __syncthreads();

  {  // LayerNorm per row + write E_new + scatter to faces
    const int rw = t >> 2, q = t & 3;
    const float* ur = Ms + rw * 133;
    float s = 0.f, s2 = 0.f;
    for (int c = q * 32; c < q * 32 + 32; ++c) { float v = ur[c]; s += v; s2 += v * v; }
    s += __shfl_xor(s, 1); s2 += __shfl_xor(s2, 1);
    s += __shfl_xor(s, 2); s2 += __shfl_xor(s2, 2);
    const float mean = s * 0.0078125f;
    const float var = s2 * 0.0078125f - mean * mean;
    const float rstd = rsqrtf(var + 1e-5f);
    const float vf = validf[rw];
    float* eo = out + (size_t)MF * DD + (size_t)(eg0 + rw) * DD;
    const int i1 = f1s[rw], i2 = f2s[rw];
    for (int c = q * 32; c < q * 32 + 32; ++c) {
      const float o = (ur[c] - mean) * rstd * ge[c] + be[c];
      eo[c] = o;
      if (vf != 0.f) {
        atomicAdd(out + (size_t)i1 * DD + c, o);
        atomicAdd(out + (size_t)i2 * DD + c, o);
      }
    }
    if (q == 0 && vf != 0.f) { atomicAdd(Fcnt + i1, 1.f); atomicAdd(Fcnt + i2, 1.f); }
  }
}

// ---------------- Face kernel: 64 faces per block, 4 waves ----------------
__global__ __launch_bounds__(256) void k_face(
    const float* __restrict__ Ffeat, const int* __restrict__ fmask,
    const unsigned short* __restrict__ W1f, const float* __restrict__ b1,
    const unsigned short* __restrict__ W2f, const float* __restrict__ b2,
    const unsigned short* __restrict__ Wgf, const float* __restrict__ bg,
    const float* __restrict__ gf, const float* __restrict__ bef,
    float* __restrict__ out, const float* __restrict__ Fcnt) {
  __shared__ unsigned short Xs[64 * 260];  // [F | msg] bf16
  __shared__ unsigned short Hs[64 * 132];  // GELU hidden bf16
  __shared__ float Us[64 * 133];           // update fp32 -> u fp32
  __shared__ float fmv[64];

  const int t = threadIdx.x;
  const int lane = t & 63;
  const int w = t >> 6;
  const int fg0 = blockIdx.x * 64;

  if (t < 64) fmv[t] = fmask[fg0 + t] ? 1.0f : 0.0f;

  {  // stage X = [F | face_msg/(cnt+eps)] as bf16
    const int row = t >> 2, q = t & 3;
    const int fg = fg0 + row;
    const float* fr = Ffeat + (size_t)fg * DD;
    const float* mr = out + (size_t)fg * DD;  // accumulated messages
    const float rinv = 1.0f / (Fcnt[fg] + 1e-8f);
    unsigned short* xr = Xs + row * 260;
    for (int c = q * 32; c < q * 32 + 32; c += 4) {
      float4 v0 = *(const float4*)(fr + c);
      float4 v1 = *(const float4*)(mr + c);
      xr[c + 0] = f2bf(v0.x); xr[c + 1] = f2bf(v0.y);
      xr[c + 2] = f2bf(v0.z); xr[c + 3] = f2bf(v0.w);
      xr[128 + c + 0] = f2bf(v1.x * rinv); xr[128 + c + 1] = f2bf(v1.y * rinv);
      xr[128 + c + 2] = f2bf(v1.z * rinv); xr[128 + c + 3] = f2bf(v1.w * rinv);
    }
  }
  __syncthreads();

  // GEMM ef1: (64x256)@(256x128) -> GELU -> Hs
  f32x4 acc[4][2] = {};
  for (int ks = 0; ks < 8; ++ks) {
    const int kb = ks * 32 + ((lane >> 4) << 2);
    bf16x8 a[4];
    for (int r = 0; r < 4; ++r)
      a[r] = ld_ab(Xs + (r * 16 + (lane & 15)) * 260 + kb);
    for (int n = 0; n < 2; ++n) {
      const int nt = (w << 1) + n;
      bf16x8 bfr = *(const bf16x8*)(W1f + (((nt * 8 + ks) << 6) + lane) * 8);
      for (int r = 0; r < 4; ++r) acc[r][n] = MFMA16(a[r], bfr, acc[r][n]);
    }
  }
  for (int n = 0; n < 2; ++n) {
    const int col = (w << 5) + (n << 4) + (lane & 15);
    const float bias = b1[col];
    for (int r = 0; r < 4; ++r)
      for (int ri = 0; ri < 4; ++ri) {
        const int rw = r * 16 + ((lane >> 4) << 2) + ri;
        Hs[rw * 132 + col] = f2bf(gelu_exact(acc[r][n][ri] + bias));
      }
  }
  __syncthreads();

  // GEMM ef2: (64x128)@(128x128) -> update fp32 in Us
  f32x4 acc2[4][2] = {};
  for (int ks = 0; ks < 4; ++ks) {
    const int kb = ks * 32 + ((lane >> 4) << 2);
    bf16x8 a[4];
    for (int r = 0; r < 4; ++r)
      a[r] = ld_ab(Hs + (r * 16 + (lane & 15)) * 132 + kb);
    for (int n = 0; n < 2; ++n) {
      const int nt = (w << 1) + n;
      bf16x8 bfr = *(const bf16x8*)(W2f + (((nt * 4 + ks) << 6) + lane) * 8);
      for (int r = 0; r < 4; ++r) acc2[r][n] = MFMA16(a[r], bfr, acc2[r][n]);
    }
  }
  for (int n = 0; n < 2; ++n) {
    const int col = (w << 5) + (n << 4) + (lane & 15);
    const float bias = b2[col];
    for (int r = 0; r < 4; ++r)
      for (int ri = 0; ri < 4; ++ri) {
        const int rw = r * 16 + ((lane >> 4) << 2) + ri;
        Us[rw * 133 + col] = acc2[r][n][ri] + bias;
      }
  }
  __syncthreads();

  // GEMM gf: [F | update](64x256)@(256x128)
  f32x4 acc3[4][2] = {};
  for (int ks = 0; ks < 8; ++ks) {
    const int kb = (ks & 3) * 32 + ((lane >> 4) << 2);
    bf16x8 a[4];
    if (ks < 4) {
      for (int r = 0; r < 4; ++r)
        a[r] = ld_ab(Xs + (r * 16 + (lane & 15)) * 260 + kb);
    } else {
      for (int r = 0; r < 4; ++r) {
        const float* p = Us + (r * 16 + (lane & 15)) * 133 + kb;
        union { unsigned short us[8]; bf16x8 v; } u;
        for (int j = 0; j < 4; ++j) { u.us[j] = f2bf(p[j]); u.us[4 + j] = f2bf(p[16 + j]); }
        a[r] = u.v;
      }
    }
    for (int n = 0; n < 2; ++n) {
      const int nt = (w << 1) + n;
      bf16x8 bfr = *(const bf16x8*)(Wgf + (((nt * 8 + ks) << 6) + lane) * 8);
      for (int r = 0; r < 4; ++r) acc3[r][n] = MFMA16(a[r], bfr, acc3[r][n]);
    }
  }
  __syncthreads();

  for (int n = 0; n < 2; ++n) {  // u = F + gate*update*mask, in place
    const int col = (w << 5) + (n << 4) + (lane & 15);
    const float bias = bg[col];
    for (int r = 0; r < 4; ++r)
      for (int ri = 0; ri < 4; ++ri) {
        const int rw = r * 16 + ((lane >> 4) << 2) + ri;
        const float gate = sigmoidf_(acc3[r][n][ri] + bias);
        const float upd = Us[rw * 133 + col];
        const float fv = Ffeat[(size_t)(fg0 + rw) * DD + col];
        Us[rw * 133 + col] = fv + gate * upd * fmv[rw];
      }
  }
  __syncthreads();

  {  // LayerNorm + write F_new (overwrites msg accumulator region)
    const int rw = t >> 2, q = t & 3;
    const float* ur = Us + rw * 133;
    float s = 0.f, s2 = 0.f;
    for (int c = q * 32; c < q * 32 + 32; ++c) { float v = ur[c]; s += v; s2 += v * v; }
    s += __shfl_xor(s, 1); s2 += __shfl_xor(s2, 1);
    s += __shfl_xor(s, 2); s2 += __shfl_xor(s2, 2);
    const float mean = s * 0.0078125f;
    const float var = s2 * 0.0078125f - mean * mean;
    const float rstd = rsqrtf(var + 1e-5f);
    float* fo = out + (size_t)(fg0 + rw) * DD;
    for (int c = q * 32; c < q * 32 + 32; ++c)
      fo[c] = (ur[c] - mean) * rstd * gf[c] + bef[c];
  }
}

extern "C" void kernel_launch(void* const* d_in, const int* in_sizes, int n_in,
                              void* d_out, int out_size, void* d_ws, size_t ws_size,
                              hipStream_t stream) {
  const float* Ffeat = (const float*)d_in[0];
  const float* Efeat = (const float*)d_in[1];
  const int* e2f = (const int*)d_in[2];
  const int* fmask = (const int*)d_in[3];
  const int* emask = (const int*)d_in[4];
  const float* w_fe1 = (const float*)d_in[5];
  const float* b_fe1 = (const float*)d_in[6];
  const float* w_fe2 = (const float*)d_in[7];
  const float* b_fe2 = (const float*)d_in[8];
  const float* w_ge = (const float*)d_in[9];
  const float* b_ge = (const float*)d_in[10];
  const float* g_e = (const float*)d_in[11];
  const float* beta_e = (const float*)d_in[12];
  const float* w_ef1 = (const float*)d_in[13];
  const float* b_ef1 = (const float*)d_in[14];
  const float* w_ef2 = (const float*)d_in[15];
  const float* b_ef2 = (const float*)d_in[16];
  const float* w_gf = (const float*)d_in[17];
  const float* b_gf = (const float*)d_in[18];
  const float* g_f = (const float*)d_in[19];
  const float* beta_f = (const float*)d_in[20];

  float* out = (float*)d_out;
  float* Fcnt = (float*)d_ws;
  unsigned short* wbase = (unsigned short*)((char*)d_ws + (size_t)MF * sizeof(float));
  unsigned short* W1f = wbase;             // 384*256
  unsigned short* W2f = W1f + 98304;       // 256*128
  unsigned short* Wgf = W2f + 32768;       // 256*128
  unsigned short* Wef1 = Wgf + 32768;      // 256*128
  unsigned short* Wef2 = Wef1 + 32768;     // 128*128
  unsigned short* Wgff = Wef2 + 16384;     // 256*128

  // F region of d_out doubles as the face-message accumulator; zero it + counts.
  hipMemsetAsync(out, 0, (size_t)MF * DD * sizeof(float), stream);
  hipMemsetAsync(Fcnt, 0, (size_t)MF * sizeof(float), stream);

  k_pack<<<(98304 + 255) / 256, 256, 0, stream>>>(w_fe1, W1f, 384, 256);
  k_pack<<<(32768 + 255) / 256, 256, 0, stream>>>(w_fe2, W2f, 256, 128);
  k_pack<<<(32768 + 255) / 256, 256, 0, stream>>>(w_ge, Wgf, 256, 128);
  k_pack<<<(32768 + 255) / 256, 256, 0, stream>>>(w_ef1, Wef1, 256, 128);
  k_pack<<<(16384 + 255) / 256, 256, 0, stream>>>(w_ef2, Wef2, 128, 128);
  k_pack<<<(32768 + 255) / 256, 256, 0, stream>>>(w_gf, Wgff, 256, 128);

  k_edge<<<ME / 64, 256, 0, stream>>>(Efeat, Ffeat, e2f, emask, W1f, b_fe1, W2f, b_fe2,
                                      Wgf, b_ge, g_e, beta_e, out, Fcnt);
  k_face<<<MF / 64, 256, 0, stream>>>(Ffeat, fmask, Wef1, b_ef1, Wef2, b_ef2,
                                      Wgff, b_gf, g_f, beta_f, out, Fcnt);
}

// Round 3
// 556.877 us; speedup vs baseline: 6.6290x; 6.6290x over previous
//
#include <hip/hip_runtime.h>

#define NB 8
#define NF 16384
#define NE 32768
#define DD 128

static constexpr int ME = NB * NE;  // 262144 edges
static constexpr int MF = NB * NF;  // 131072 faces

typedef short bf16x8 __attribute__((ext_vector_type(8)));
typedef float f32x4 __attribute__((ext_vector_type(4)));

#define MFMA16(a, b, c) __builtin_amdgcn_mfma_f32_16x16x32_bf16((a), (b), (c), 0, 0, 0)

static __device__ __forceinline__ unsigned short f2bf(float f) {
  union { float f; unsigned u; } v; v.f = f;
  unsigned r = (v.u + 0x7fffu + ((v.u >> 16) & 1u)) >> 16;
  return (unsigned short)r;
}
static __device__ __forceinline__ float bf2f(unsigned short h) {
  union { unsigned u; float f; } v; v.u = ((unsigned)h) << 16;
  return v.f;
}
static __device__ __forceinline__ bf16x8 pack8(float4 a, float4 b) {
  bf16x8 r;
  r[0] = (short)f2bf(a.x); r[1] = (short)f2bf(a.y);
  r[2] = (short)f2bf(a.z); r[3] = (short)f2bf(a.w);
  r[4] = (short)f2bf(b.x); r[5] = (short)f2bf(b.y);
  r[6] = (short)f2bf(b.z); r[7] = (short)f2bf(b.w);
  return r;
}

// A/B fragment: elements j0..3 at k=kb..kb+3, j4..7 at k=kb+16..kb+19
static __device__ __forceinline__ bf16x8 ld_ab(const unsigned short* p) {
  union { unsigned long long q[2]; bf16x8 v; } u;
  u.q[0] = *(const unsigned long long*)(p);
  u.q[1] = *(const unsigned long long*)(p + 16);
  return u.v;
}

static __device__ __forceinline__ float gelu_exact(float x) {
  return 0.5f * x * (1.0f + erff(x * 0.70710678118654752f));
}
static __device__ __forceinline__ float sigmoidf_(float x) {
  return 1.0f / (1.0f + expf(-x));
}

// Pack fp32 weight (K,N) row-major into bf16 MFMA B-fragment order:
// Wf[((nt*KS + ks)*64 + lane)*8 + j], col = nt*16 + (lane&15),
// k = ks*32 + 16*(j>>2) + 4*(lane>>4) + (j&3)   (same k-map as ld_ab)
__global__ void k_pack(const float* __restrict__ W, unsigned short* __restrict__ Wf,
                       int K, int N) {
  int idx = blockIdx.x * 256 + threadIdx.x;
  if (idx >= K * N) return;
  int j = idx & 7;
  int lane = (idx >> 3) & 63;
  int rest = idx >> 9;
  int KS = K >> 5;
  int ks = rest % KS;
  int nt = rest / KS;
  int col = nt * 16 + (lane & 15);
  int kk = ks * 32 + ((j >> 2) << 4) + ((lane >> 4) << 2) + (j & 3);
  Wf[idx] = f2bf(W[kk * N + col]);
}

// ---------------- Edge kernel: 64 edges/block, 4 waves, 2 blocks/CU ----------------
// LDS pool (69376 B):
//   Xe  u16 [64] pitch 136  @0       (17408)  E bf16; live through GEMM3 ks<4
//   Xf  u16 [64] pitch 264  @17408   (33792)  F1|F2; GEMM1 only
//   H   u16 [64] pitch 260  @17408            hidden (aliases Xf)
//   M   f32 [64] pitch 132  @17408            msg fp32 -> u fp32 (aliases H)
//   Mb  u16 [64] pitch 132  @51200   (16896)  msg bf16 for GEMM3 A
//   G   u16 [64] pitch 132  @51200            gate bf16 (aliases Mb)
//   aux @68096: f1s[64] f2s[64] validf[64] mu[64] rs[64]
__global__ __launch_bounds__(256, 2) void k_edge(
    const float* __restrict__ Efeat, const float* __restrict__ Ffeat,
    const int* __restrict__ e2f, const int* __restrict__ emask,
    const unsigned short* __restrict__ W1f, const float* __restrict__ b1,
    const unsigned short* __restrict__ W2f, const float* __restrict__ b2,
    const unsigned short* __restrict__ Wgf, const float* __restrict__ bg,
    const float* __restrict__ ge, const float* __restrict__ be,
    float* __restrict__ out, float* __restrict__ Fcnt) {
  __shared__ __align__(16) unsigned char pool[69376];
  unsigned short* Xe = (unsigned short*)pool;             // pitch 136
  unsigned short* Xf = (unsigned short*)(pool + 17408);   // pitch 264
  unsigned short* H  = (unsigned short*)(pool + 17408);   // pitch 260
  float*          M  = (float*)(pool + 17408);            // pitch 132
  unsigned short* Mb = (unsigned short*)(pool + 51200);   // pitch 132
  unsigned short* G  = (unsigned short*)(pool + 51200);   // pitch 132
  int*   f1s    = (int*)(pool + 68096);
  int*   f2s    = (int*)(pool + 68352);
  float* validf = (float*)(pool + 68608);
  float* mu     = (float*)(pool + 68864);
  float* rs     = (float*)(pool + 69120);

  const int t = threadIdx.x;
  const int lane = t & 63;
  const int w = t >> 6;
  const int l15 = lane & 15;
  const int l4 = lane >> 4;
  const int eg0 = blockIdx.x * 64;

  if (t < 64) {
    const int eg = eg0 + t;
    const int b = eg >> 15;  // / NE
    const int r1 = e2f[2 * eg], r2 = e2f[2 * eg + 1];
    const bool v = (emask[eg] != 0) && (r1 >= 0) && (r2 >= 0);
    int f1 = r1 < 0 ? 0 : (r1 > NF - 1 ? NF - 1 : r1);
    int f2 = r2 < 0 ? 0 : (r2 > NF - 1 ? NF - 1 : r2);
    f1s[t] = b * NF + f1;
    f2s[t] = b * NF + f2;
    validf[t] = v ? 1.0f : 0.0f;
    if (v) {  // face counts (order vs face kernel guaranteed by stream)
      atomicAdd(Fcnt + b * NF + f1, 1.0f);
      atomicAdd(Fcnt + b * NF + f2, 1.0f);
    }
  }
  __syncthreads();

  // ---- staging: 16B chunks, coalesced global, b128 LDS stores ----
  for (int k = 0; k < 4; ++k) {  // E rows (block-contiguous in global)
    const int c = k * 256 + t, row = c >> 4, j = c & 15;
    const float* s = Efeat + (size_t)(eg0 + row) * DD + j * 8;
    *(bf16x8*)(Xe + row * 136 + j * 8) =
        pack8(*(const float4*)s, *(const float4*)(s + 4));
  }
  for (int k = 0; k < 4; ++k) {  // F1 | F2 gathered rows
    const int c = k * 256 + t, row = c >> 4, j = c & 15;
    const float* s1 = Ffeat + (size_t)f1s[row] * DD + j * 8;
    const float* s2 = Ffeat + (size_t)f2s[row] * DD + j * 8;
    *(bf16x8*)(Xf + row * 264 + j * 8) =
        pack8(*(const float4*)s1, *(const float4*)(s1 + 4));
    *(bf16x8*)(Xf + row * 264 + 128 + j * 8) =
        pack8(*(const float4*)s2, *(const float4*)(s2 + 4));
  }
  __syncthreads();

  // ---- GEMM1: (64x384)@(384x256), wave w -> cols [64w, 64w+64) ----
  {
    f32x4 acc[4][4] = {};
    for (int ks = 0; ks < 12; ++ks) {
      bf16x8 a[4];
      if (ks < 4) {
        const int kb = ks * 32 + (l4 << 2);
        for (int r = 0; r < 4; ++r) a[r] = ld_ab(Xe + (r * 16 + l15) * 136 + kb);
      } else {
        const int kb = (ks - 4) * 32 + (l4 << 2);
        for (int r = 0; r < 4; ++r) a[r] = ld_ab(Xf + (r * 16 + l15) * 264 + kb);
      }
      for (int n = 0; n < 4; ++n) {
        const int nt = (w << 2) + n;
        bf16x8 bfr = *(const bf16x8*)(W1f + (((nt * 12 + ks) << 6) + lane) * 8);
        for (int r = 0; r < 4; ++r) acc[r][n] = MFMA16(a[r], bfr, acc[r][n]);
      }
    }
    __syncthreads();  // Xf fully read; H may overwrite it
    for (int n = 0; n < 4; ++n) {
      const int col = (w << 6) + (n << 4) + l15;
      const float bias = b1[col];
      for (int r = 0; r < 4; ++r)
        for (int ri = 0; ri < 4; ++ri) {
          const int rw = r * 16 + (l4 << 2) + ri;
          H[rw * 260 + col] = f2bf(gelu_exact(acc[r][n][ri] + bias));
        }
    }
  }
  __syncthreads();

  // ---- GEMM2: (64x256)@(256x128), wave w -> cols [32w, 32w+32) ----
  {
    f32x4 acc2[4][2] = {};
    for (int ks = 0; ks < 8; ++ks) {
      const int kb = ks * 32 + (l4 << 2);
      bf16x8 a[4];
      for (int r = 0; r < 4; ++r) a[r] = ld_ab(H + (r * 16 + l15) * 260 + kb);
      for (int n = 0; n < 2; ++n) {
        const int nt = (w << 1) + n;
        bf16x8 bfr = *(const bf16x8*)(W2f + (((nt * 8 + ks) << 6) + lane) * 8);
        for (int r = 0; r < 4; ++r) acc2[r][n] = MFMA16(a[r], bfr, acc2[r][n]);
      }
    }
    __syncthreads();  // H fully read; M may overwrite it
    for (int n = 0; n < 2; ++n) {
      const int col = (w << 5) + (n << 4) + l15;
      const float bias = b2[col];
      for (int r = 0; r < 4; ++r)
        for (int ri = 0; ri < 4; ++ri) {
          const int rw = r * 16 + (l4 << 2) + ri;
          const float mv = (acc2[r][n][ri] + bias) * validf[rw];
          M[rw * 132 + col] = mv;
          Mb[rw * 132 + col] = f2bf(mv);
        }
    }
  }
  __syncthreads();

  // ---- GEMM3 (gate): [E | msg](64x256)@(256x128) ----
  {
    f32x4 acc3[4][2] = {};
    for (int ks = 0; ks < 8; ++ks) {
      bf16x8 a[4];
      if (ks < 4) {
        const int kb = ks * 32 + (l4 << 2);
        for (int r = 0; r < 4; ++r) a[r] = ld_ab(Xe + (r * 16 + l15) * 136 + kb);
      } else {
        const int kb = (ks - 4) * 32 + (l4 << 2);
        for (int r = 0; r < 4; ++r) a[r] = ld_ab(Mb + (r * 16 + l15) * 132 + kb);
      }
      for (int n = 0; n < 2; ++n) {
        const int nt = (w << 1) + n;
        bf16x8 bfr = *(const bf16x8*)(Wgf + (((nt * 8 + ks) << 6) + lane) * 8);
        for (int r = 0; r < 4; ++r) acc3[r][n] = MFMA16(a[r], bfr, acc3[r][n]);
      }
    }
    __syncthreads();  // Mb fully read; G may overwrite it
    for (int n = 0; n < 2; ++n) {
      const int col = (w << 5) + (n << 4) + l15;
      const float bias = bg[col];
      for (int r = 0; r < 4; ++r)
        for (int ri = 0; ri < 4; ++ri) {
          const int rw = r * 16 + (l4 << 2) + ri;
          G[rw * 132 + col] = f2bf(sigmoidf_(acc3[r][n][ri] + bias));
        }
    }
  }
  __syncthreads();

  // ---- u = E + gate*msg (coalesced Efeat read; in place into M) ----
  const int colc = t & 127;
  const int rb = t >> 7;  // wave-uniform
  const float gec = ge[colc], bec = be[colc];
  for (int i = 0; i < 32; ++i) {
    const int row = 2 * i + rb;
    const float ev = Efeat[(size_t)(eg0 + row) * DD + colc];
    const float gv = bf2f(G[row * 132 + colc]);
    const float mv = M[row * 132 + colc];
    M[row * 132 + colc] = ev + gv * mv;
  }
  __syncthreads();

  {  // ---- LN stats (conflict-free b128 reads) ----
    const int rw = t >> 2, q = t & 3;
    const float* ur = M + rw * 132 + q * 32;
    float s = 0.f, s2 = 0.f;
    for (int j = 0; j < 8; ++j) {
      float4 v = *(const float4*)(ur + 4 * j);
      s += v.x + v.y + v.z + v.w;
      s2 += v.x * v.x + v.y * v.y + v.z * v.z + v.w * v.w;
    }
    s += __shfl_xor(s, 1); s2 += __shfl_xor(s2, 1);
    s += __shfl_xor(s, 2); s2 += __shfl_xor(s2, 2);
    if (q == 0) {
      const float mean = s * 0.0078125f;
      const float var = s2 * 0.0078125f - mean * mean;
      mu[rw] = mean;
      rs[rw] = rsqrtf(var + 1e-5f);
    }
  }
  __syncthreads();

  // ---- epilogue: coalesced E_new store + coalesced scatter atomics ----
  float* eob = out + (size_t)MF * DD;
  for (int i = 0; i < 32; ++i) {
    const int row = 2 * i + rb;  // wave-uniform
    const float o = (M[row * 132 + colc] - mu[row]) * rs[row] * gec + bec;
    eob[(size_t)(eg0 + row) * DD + colc] = o;
    if (validf[row] != 0.f) {
      atomicAdd(out + (size_t)f1s[row] * DD + colc, o);
      atomicAdd(out + (size_t)f2s[row] * DD + colc, o);
    }
  }
}

// ---------------- Face kernel: 64 faces/block, 4 waves, 2 blocks/CU ----------------
// LDS pool (68608 B):
//   X  u16 [64] pitch 264 @0      (33792)  [F | msg] bf16
//   G  u16 [64] pitch 132 @0               gate bf16 (aliases X)
//   H  u16 [64] pitch 132 @33792  (16896)  hidden bf16
//   U  f32 [64] pitch 132 @33792  (33792)  update fp32 -> u fp32 (aliases H)
//   aux @67584: fmv[64] rv[64] mu[64] rs[64]
__global__ __launch_bounds__(256, 2) void k_face(
    const float* __restrict__ Ffeat, const int* __restrict__ fmask,
    const unsigned short* __restrict__ W1f, const float* __restrict__ b1,
    const unsigned short* __restrict__ W2f, const float* __restrict__ b2,
    const unsigned short* __restrict__ Wgf, const float* __restrict__ bg,
    const float* __restrict__ gf, const float* __restrict__ bef,
    float* __restrict__ out, const float* __restrict__ Fcnt) {
  __shared__ __align__(16) unsigned char pool[68608];
  unsigned short* X = (unsigned short*)pool;              // pitch 264
  unsigned short* G = (unsigned short*)pool;              // pitch 132
  unsigned short* H = (unsigned short*)(pool + 33792);    // pitch 132
  float*          U = (float*)(pool + 33792);             // pitch 132
  float* fmv = (float*)(pool + 67584);
  float* rv  = (float*)(pool + 67840);
  float* mu  = (float*)(pool + 68096);
  float* rs  = (float*)(pool + 68352);

  const int t = threadIdx.x;
  const int lane = t & 63;
  const int w = t >> 6;
  const int l15 = lane & 15;
  const int l4 = lane >> 4;
  const int fg0 = blockIdx.x * 64;

  if (t < 64) {
    fmv[t] = fmask[fg0 + t] ? 1.0f : 0.0f;
    rv[t] = 1.0f / (Fcnt[fg0 + t] + 1e-8f);
  }
  __syncthreads();

  // ---- staging: X = [F | msg*rinv] ----
  for (int k = 0; k < 4; ++k) {
    const int c = k * 256 + t, row = c >> 4, j = c & 15;
    const float* sf = Ffeat + (size_t)(fg0 + row) * DD + j * 8;
    const float* sm = out + (size_t)(fg0 + row) * DD + j * 8;  // accumulated msgs
    *(bf16x8*)(X + row * 264 + j * 8) =
        pack8(*(const float4*)sf, *(const float4*)(sf + 4));
    const float ri = rv[row];
    float4 m0 = *(const float4*)sm, m1 = *(const float4*)(sm + 4);
    m0.x *= ri; m0.y *= ri; m0.z *= ri; m0.w *= ri;
    m1.x *= ri; m1.y *= ri; m1.z *= ri; m1.w *= ri;
    *(bf16x8*)(X + row * 264 + 128 + j * 8) = pack8(m0, m1);
  }
  __syncthreads();

  // ---- GEMM ef1: (64x256)@(256x128) -> GELU -> H ----
  {
    f32x4 acc[4][2] = {};
    for (int ks = 0; ks < 8; ++ks) {
      const int kb = ks * 32 + (l4 << 2);
      bf16x8 a[4];
      for (int r = 0; r < 4; ++r) a[r] = ld_ab(X + (r * 16 + l15) * 264 + kb);
      for (int n = 0; n < 2; ++n) {
        const int nt = (w << 1) + n;
        bf16x8 bfr = *(const bf16x8*)(W1f + (((nt * 8 + ks) << 6) + lane) * 8);
        for (int r = 0; r < 4; ++r) acc[r][n] = MFMA16(a[r], bfr, acc[r][n]);
      }
    }
    for (int n = 0; n < 2; ++n) {
      const int col = (w << 5) + (n << 4) + l15;
      const float bias = b1[col];
      for (int r = 0; r < 4; ++r)
        for (int ri = 0; ri < 4; ++ri) {
          const int rw = r * 16 + (l4 << 2) + ri;
          H[rw * 132 + col] = f2bf(gelu_exact(acc[r][n][ri] + bias));
        }
    }
  }
  __syncthreads();

  // ---- GEMM ef2: (64x128)@(128x128) -> U fp32 ----
  {
    f32x4 acc2[4][2] = {};
    for (int ks = 0; ks < 4; ++ks) {
      const int kb = ks * 32 + (l4 << 2);
      bf16x8 a[4];
      for (int r = 0; r < 4; ++r) a[r] = ld_ab(H + (r * 16 + l15) * 132 + kb);
      for (int n = 0; n < 2; ++n) {
        const int nt = (w << 1) + n;
        bf16x8 bfr = *(const bf16x8*)(W2f + (((nt * 4 + ks) << 6) + lane) * 8);
        for (int r = 0; r < 4; ++r) acc2[r][n] = MFMA16(a[r], bfr, acc2[r][n]);
      }
    }
    __syncthreads();  // H fully read; U may overwrite it
    for (int n = 0; n < 2; ++n) {
      const int col = (w << 5) + (n << 4) + l15;
      const float bias = b2[col];
      for (int r = 0; r < 4; ++r)
        for (int ri = 0; ri < 4; ++ri) {
          const int rw = r * 16 + (l4 << 2) + ri;
          U[rw * 132 + col] = acc2[r][n][ri] + bias;
        }
    }
  }
  __syncthreads();

  // ---- GEMM gf: [F | update](64x256)@(256x128) ----
  {
    f32x4 acc3[4][2] = {};
    for (int ks = 0; ks < 8; ++ks) {
      bf16x8 a[4];
      if (ks < 4) {
        const int kb = ks * 32 + (l4 << 2);
        for (int r = 0; r < 4; ++r) a[r] = ld_ab(X + (r * 16 + l15) * 264 + kb);
      } else {
        const int kb = (ks - 4) * 32 + (l4 << 2);
        for (int r = 0; r < 4; ++r) {
          const float* p = U + (r * 16 + l15) * 132 + kb;
          union { unsigned short us[8]; bf16x8 v; } u;
          for (int j = 0; j < 4; ++j) { u.us[j] = f2bf(p[j]); u.us[4 + j] = f2bf(p[16 + j]); }
          a[r] = u.v;
        }
      }
      for (int n = 0; n < 2; ++n) {
        const int nt = (w << 1) + n;
        bf16x8 bfr = *(const bf16x8*)(Wgf + (((nt * 8 + ks) << 6) + lane) * 8);
        for (int r = 0; r < 4; ++r) acc3[r][n] = MFMA16(a[r], bfr, acc3[r][n]);
      }
    }
    __syncthreads();  // X fully read; G may overwrite it
    for (int n = 0; n < 2; ++n) {
      const int col = (w << 5) + (n << 4) + l15;
      const float bias = bg[col];
      for (int r = 0; r < 4; ++r)
        for (int ri = 0; ri < 4; ++ri) {
          const int rw = r * 16 + (l4 << 2) + ri;
          G[rw * 132 + col] = f2bf(sigmoidf_(acc3[r][n][ri] + bias));
        }
    }
  }
  __syncthreads();

  // ---- u = F + gate*update*mask (coalesced) ----
  const int colc = t & 127;
  const int rb = t >> 7;
  const float gfc = gf[colc], bfc = bef[colc];
  for (int i = 0; i < 32; ++i) {
    const int row = 2 * i + rb;
    const float fv = Ffeat[(size_t)(fg0 + row) * DD + colc];
    const float gv = bf2f(G[row * 132 + colc]);
    const float uv = U[row * 132 + colc];
    U[row * 132 + colc] = fv + gv * uv * fmv[row];
  }
  __syncthreads();

  {  // ---- LN stats ----
    const int rw = t >> 2, q = t & 3;
    const float* ur = U + rw * 132 + q * 32;
    float s = 0.f, s2 = 0.f;
    for (int j = 0; j < 8; ++j) {
      float4 v = *(const float4*)(ur + 4 * j);
      s += v.x + v.y + v.z + v.w;
      s2 += v.x * v.x + v.y * v.y + v.z * v.z + v.w * v.w;
    }
    s += __shfl_xor(s, 1); s2 += __shfl_xor(s2, 1);
    s += __shfl_xor(s, 2); s2 += __shfl_xor(s2, 2);
    if (q == 0) {
      const float mean = s * 0.0078125f;
      const float var = s2 * 0.0078125f - mean * mean;
      mu[rw] = mean;
      rs[rw] = rsqrtf(var + 1e-5f);
    }
  }
  __syncthreads();

  // ---- epilogue: coalesced F_new store (overwrites msg accumulator) ----
  for (int i = 0; i < 32; ++i) {
    const int row = 2 * i + rb;
    const float o = (U[row * 132 + colc] - mu[row]) * rs[row] * gfc + bfc;
    out[(size_t)(fg0 + row) * DD + colc] = o;
  }
}

extern "C" void kernel_launch(void* const* d_in, const int* in_sizes, int n_in,
                              void* d_out, int out_size, void* d_ws, size_t ws_size,
                              hipStream_t stream) {
  const float* Ffeat = (const float*)d_in[0];
  const float* Efeat = (const float*)d_in[1];
  const int* e2f = (const int*)d_in[2];
  const int* fmask = (const int*)d_in[3];
  const int* emask = (const int*)d_in[4];
  const float* w_fe1 = (const float*)d_in[5];
  const float* b_fe1 = (const float*)d_in[6];
  const float* w_fe2 = (const float*)d_in[7];
  const float* b_fe2 = (const float*)d_in[8];
  const float* w_ge = (const float*)d_in[9];
  const float* b_ge = (const float*)d_in[10];
  const float* g_e = (const float*)d_in[11];
  const float* beta_e = (const float*)d_in[12];
  const float* w_ef1 = (const float*)d_in[13];
  const float* b_ef1 = (const float*)d_in[14];
  const float* w_ef2 = (const float*)d_in[15];
  const float* b_ef2 = (const float*)d_in[16];
  const float* w_gf = (const float*)d_in[17];
  const float* b_gf = (const float*)d_in[18];
  const float* g_f = (const float*)d_in[19];
  const float* beta_f = (const float*)d_in[20];

  float* out = (float*)d_out;
  float* Fcnt = (float*)d_ws;
  unsigned short* wbase = (unsigned short*)((char*)d_ws + (size_t)MF * sizeof(float));
  unsigned short* W1f = wbase;             // 384*256
  unsigned short* W2f = W1f + 98304;       // 256*128
  unsigned short* Wgf = W2f + 32768;       // 256*128
  unsigned short* Wef1 = Wgf + 32768;      // 256*128
  unsigned short* Wef2 = Wef1 + 32768;     // 128*128
  unsigned short* Wgff = Wef2 + 16384;     // 256*128

  // F region of d_out doubles as the face-message accumulator; zero it + counts.
  hipMemsetAsync(out, 0, (size_t)MF * DD * sizeof(float), stream);
  hipMemsetAsync(Fcnt, 0, (size_t)MF * sizeof(float), stream);

  k_pack<<<(98304 + 255) / 256, 256, 0, stream>>>(w_fe1, W1f, 384, 256);
  k_pack<<<(32768 + 255) / 256, 256, 0, stream>>>(w_fe2, W2f, 256, 128);
  k_pack<<<(32768 + 255) / 256, 256, 0, stream>>>(w_ge, Wgf, 256, 128);
  k_pack<<<(32768 + 255) / 256, 256, 0, stream>>>(w_ef1, Wef1, 256, 128);
  k_pack<<<(16384 + 255) / 256, 256, 0, stream>>>(w_ef2, Wef2, 128, 128);
  k_pack<<<(32768 + 255) / 256, 256, 0, stream>>>(w_gf, Wgff, 256, 128);

  k_edge<<<ME / 64, 256, 0, stream>>>(Efeat, Ffeat, e2f, emask, W1f, b_fe1, W2f, b_fe2,
                                      Wgf, b_ge, g_e, beta_e, out, Fcnt);
  k_face<<<MF / 64, 256, 0, stream>>>(Ffeat, fmask, Wef1, b_ef1, Wef2, b_ef2,
                                      Wgff, b_gf, g_f, beta_f, out, Fcnt);
}

// Round 4
// 457.576 us; speedup vs baseline: 8.0675x; 1.2170x over previous
//
#include <hip/hip_runtime.h>

#define NB 8
#define NF 16384
#define NE 32768
#define DD 128

static constexpr int ME = NB * NE;  // 262144 edges
static constexpr int MF = NB * NF;  // 131072 faces

typedef short bf16x8 __attribute__((ext_vector_type(8)));
typedef float f32x4 __attribute__((ext_vector_type(4)));

#define MFMA16(a, b, c) __builtin_amdgcn_mfma_f32_16x16x32_bf16((a), (b), (c), 0, 0, 0)

static __device__ __forceinline__ unsigned short f2bf(float f) {
  union { float f; unsigned u; } v; v.f = f;
  unsigned r = (v.u + 0x7fffu + ((v.u >> 16) & 1u)) >> 16;
  return (unsigned short)r;
}
static __device__ __forceinline__ float bf2f(unsigned short h) {
  union { unsigned u; float f; } v; v.u = ((unsigned)h) << 16;
  return v.f;
}
static __device__ __forceinline__ bf16x8 pack8(float4 a, float4 b) {
  bf16x8 r;
  r[0] = (short)f2bf(a.x); r[1] = (short)f2bf(a.y);
  r[2] = (short)f2bf(a.z); r[3] = (short)f2bf(a.w);
  r[4] = (short)f2bf(b.x); r[5] = (short)f2bf(b.y);
  r[6] = (short)f2bf(b.z); r[7] = (short)f2bf(b.w);
  return r;
}

// A/B fragment: elements j0..3 at k=kb..kb+3, j4..7 at k=kb+16..kb+19
static __device__ __forceinline__ bf16x8 ld_ab(const unsigned short* p) {
  union { unsigned long long q[2]; bf16x8 v; } u;
  u.q[0] = *(const unsigned long long*)(p);
  u.q[1] = *(const unsigned long long*)(p + 16);
  return u.v;
}

static __device__ __forceinline__ float gelu_exact(float x) {
  return 0.5f * x * (1.0f + erff(x * 0.70710678118654752f));
}
static __device__ __forceinline__ float sigmoidf_(float x) {
  return 1.0f / (1.0f + expf(-x));
}

// Pack fp32 weight (K,N) row-major into bf16 MFMA B-fragment order:
// Wf[((nt*KS + ks)*64 + lane)*8 + j], col = nt*16 + (lane&15),
// k = ks*32 + 16*(j>>2) + 4*(lane>>4) + (j&3)   (same k-map as ld_ab)
__global__ void k_pack(const float* __restrict__ W, unsigned short* __restrict__ Wf,
                       int K, int N) {
  int idx = blockIdx.x * 256 + threadIdx.x;
  if (idx >= K * N) return;
  int j = idx & 7;
  int lane = (idx >> 3) & 63;
  int rest = idx >> 9;
  int KS = K >> 5;
  int ks = rest % KS;
  int nt = rest / KS;
  int col = nt * 16 + (lane & 15);
  int kk = ks * 32 + ((j >> 2) << 4) + ((lane >> 4) << 2) + (j & 3);
  Wf[idx] = f2bf(W[kk * N + col]);
}

// ---------------- Edge kernel: 64 edges/block, 8 waves, 2 blocks/CU ----------------
// LDS pool (69376 B):
//   Xe  u16 [64] pitch 136  @0       (17408)  E bf16; live through GEMM3 ks<4
//   Xf  u16 [64] pitch 264  @17408   (33792)  F1|F2; GEMM1 only
//   H   u16 [64] pitch 260  @17408            hidden (aliases Xf)
//   M   f32 [64] pitch 132  @17408            msg fp32 -> u fp32 (aliases H)
//   Mb  u16 [64] pitch 132  @51200   (16896)  msg bf16 for GEMM3 A
//   G   u16 [64] pitch 132  @51200            gate bf16 (aliases Mb)
//   aux @68096: f1s[64] f2s[64] validf[64] mu[64] rs[64]
__global__ __launch_bounds__(512, 4) void k_edge(
    const float* __restrict__ Efeat, const float* __restrict__ Ffeat,
    const int* __restrict__ e2f, const int* __restrict__ emask,
    const unsigned short* __restrict__ W1f, const float* __restrict__ b1,
    const unsigned short* __restrict__ W2f, const float* __restrict__ b2,
    const unsigned short* __restrict__ Wgf, const float* __restrict__ bg,
    const float* __restrict__ ge, const float* __restrict__ be,
    float* __restrict__ out, float* __restrict__ Fcnt) {
  __shared__ __align__(16) unsigned char pool[69376];
  unsigned short* Xe = (unsigned short*)pool;             // pitch 136
  unsigned short* Xf = (unsigned short*)(pool + 17408);   // pitch 264
  unsigned short* H  = (unsigned short*)(pool + 17408);   // pitch 260
  float*          M  = (float*)(pool + 17408);            // pitch 132
  unsigned short* Mb = (unsigned short*)(pool + 51200);   // pitch 132
  unsigned short* G  = (unsigned short*)(pool + 51200);   // pitch 132
  int*   f1s    = (int*)(pool + 68096);
  int*   f2s    = (int*)(pool + 68352);
  float* validf = (float*)(pool + 68608);
  float* mu     = (float*)(pool + 68864);
  float* rs     = (float*)(pool + 69120);

  const int t = threadIdx.x;
  const int lane = t & 63;
  const int w = t >> 6;   // 0..7
  const int l15 = lane & 15;
  const int l4 = lane >> 4;
  const int eg0 = blockIdx.x * 64;

  if (t < 64) {
    const int eg = eg0 + t;
    const int b = eg >> 15;  // / NE
    const int r1 = e2f[2 * eg], r2 = e2f[2 * eg + 1];
    const bool v = (emask[eg] != 0) && (r1 >= 0) && (r2 >= 0);
    int f1 = r1 < 0 ? 0 : (r1 > NF - 1 ? NF - 1 : r1);
    int f2 = r2 < 0 ? 0 : (r2 > NF - 1 ? NF - 1 : r2);
    f1s[t] = b * NF + f1;
    f2s[t] = b * NF + f2;
    validf[t] = v ? 1.0f : 0.0f;
    if (v) {  // face counts (order vs face kernel guaranteed by stream)
      atomicAdd(Fcnt + b * NF + f1, 1.0f);
      atomicAdd(Fcnt + b * NF + f2, 1.0f);
    }
  }
  __syncthreads();

  // ---- staging: 16B chunks, coalesced global, b128 LDS stores ----
  for (int k = 0; k < 2; ++k) {  // E rows (block-contiguous in global)
    const int c = k * 512 + t, row = c >> 4, j = c & 15;
    const float* s = Efeat + (size_t)(eg0 + row) * DD + j * 8;
    *(bf16x8*)(Xe + row * 136 + j * 8) =
        pack8(*(const float4*)s, *(const float4*)(s + 4));
  }
  for (int k = 0; k < 2; ++k) {  // F1 gathered rows
    const int c = k * 512 + t, row = c >> 4, j = c & 15;
    const float* s1 = Ffeat + (size_t)f1s[row] * DD + j * 8;
    *(bf16x8*)(Xf + row * 264 + j * 8) =
        pack8(*(const float4*)s1, *(const float4*)(s1 + 4));
  }
  for (int k = 0; k < 2; ++k) {  // F2 gathered rows
    const int c = k * 512 + t, row = c >> 4, j = c & 15;
    const float* s2 = Ffeat + (size_t)f2s[row] * DD + j * 8;
    *(bf16x8*)(Xf + row * 264 + 128 + j * 8) =
        pack8(*(const float4*)s2, *(const float4*)(s2 + 4));
  }
  __syncthreads();

  // ---- GEMM1: (64x384)@(384x256), wave w -> cols [32w, 32w+32) ----
  {
    f32x4 acc[4][2] = {};
    for (int ks = 0; ks < 12; ++ks) {
      bf16x8 a[4];
      if (ks < 4) {
        const int kb = ks * 32 + (l4 << 2);
        for (int r = 0; r < 4; ++r) a[r] = ld_ab(Xe + (r * 16 + l15) * 136 + kb);
      } else {
        const int kb = (ks - 4) * 32 + (l4 << 2);
        for (int r = 0; r < 4; ++r) a[r] = ld_ab(Xf + (r * 16 + l15) * 264 + kb);
      }
      for (int n = 0; n < 2; ++n) {
        const int nt = (w << 1) + n;
        bf16x8 bfr = *(const bf16x8*)(W1f + (((nt * 12 + ks) << 6) + lane) * 8);
        for (int r = 0; r < 4; ++r) acc[r][n] = MFMA16(a[r], bfr, acc[r][n]);
      }
    }
    __syncthreads();  // Xf fully read; H may overwrite it
    for (int n = 0; n < 2; ++n) {
      const int col = (w << 5) + (n << 4) + l15;
      const float bias = b1[col];
      for (int r = 0; r < 4; ++r)
        for (int ri = 0; ri < 4; ++ri) {
          const int rw = r * 16 + (l4 << 2) + ri;
          H[rw * 260 + col] = f2bf(gelu_exact(acc[r][n][ri] + bias));
        }
    }
  }
  __syncthreads();

  // ---- GEMM2: (64x256)@(256x128), wave w -> cols [16w, 16w+16) ----
  {
    f32x4 acc2[4] = {};
    for (int ks = 0; ks < 8; ++ks) {
      const int kb = ks * 32 + (l4 << 2);
      bf16x8 a[4];
      for (int r = 0; r < 4; ++r) a[r] = ld_ab(H + (r * 16 + l15) * 260 + kb);
      bf16x8 bfr = *(const bf16x8*)(W2f + (((w * 8 + ks) << 6) + lane) * 8);
      for (int r = 0; r < 4; ++r) acc2[r] = MFMA16(a[r], bfr, acc2[r]);
    }
    __syncthreads();  // H fully read; M may overwrite it
    const int col = (w << 4) + l15;
    const float bias = b2[col];
    for (int r = 0; r < 4; ++r)
      for (int ri = 0; ri < 4; ++ri) {
        const int rw = r * 16 + (l4 << 2) + ri;
        const float mv = (acc2[r][ri] + bias) * validf[rw];
        M[rw * 132 + col] = mv;
        Mb[rw * 132 + col] = f2bf(mv);
      }
  }
  __syncthreads();

  // ---- GEMM3 (gate): [E | msg](64x256)@(256x128), wave w -> cols [16w,16w+16) ----
  {
    f32x4 acc3[4] = {};
    for (int ks = 0; ks < 8; ++ks) {
      bf16x8 a[4];
      if (ks < 4) {
        const int kb = ks * 32 + (l4 << 2);
        for (int r = 0; r < 4; ++r) a[r] = ld_ab(Xe + (r * 16 + l15) * 136 + kb);
      } else {
        const int kb = (ks - 4) * 32 + (l4 << 2);
        for (int r = 0; r < 4; ++r) a[r] = ld_ab(Mb + (r * 16 + l15) * 132 + kb);
      }
      bf16x8 bfr = *(const bf16x8*)(Wgf + (((w * 8 + ks) << 6) + lane) * 8);
      for (int r = 0; r < 4; ++r) acc3[r] = MFMA16(a[r], bfr, acc3[r]);
    }
    __syncthreads();  // Mb fully read; G may overwrite it
    const int col = (w << 4) + l15;
    const float bias = bg[col];
    for (int r = 0; r < 4; ++r)
      for (int ri = 0; ri < 4; ++ri) {
        const int rw = r * 16 + (l4 << 2) + ri;
        G[rw * 132 + col] = f2bf(sigmoidf_(acc3[r][ri] + bias));
      }
  }
  __syncthreads();

  // ---- u = E + gate*msg (coalesced Efeat read; in place into M) ----
  const int colc = t & 127;
  const int rb = t >> 7;  // wave-uniform, 0..3
  const float gec = ge[colc], bec = be[colc];
  for (int i = 0; i < 16; ++i) {
    const int row = 4 * i + rb;
    const float ev = Efeat[(size_t)(eg0 + row) * DD + colc];
    const float gv = bf2f(G[row * 132 + colc]);
    const float mv = M[row * 132 + colc];
    M[row * 132 + colc] = ev + gv * mv;
  }
  __syncthreads();

  {  // ---- LN stats: 8 threads/row ----
    const int rw = t >> 3, q = t & 7;
    const float* ur = M + rw * 132 + q * 16;
    float s = 0.f, s2 = 0.f;
    for (int j = 0; j < 4; ++j) {
      float4 v = *(const float4*)(ur + 4 * j);
      s += v.x + v.y + v.z + v.w;
      s2 += v.x * v.x + v.y * v.y + v.z * v.z + v.w * v.w;
    }
    s += __shfl_xor(s, 1); s2 += __shfl_xor(s2, 1);
    s += __shfl_xor(s, 2); s2 += __shfl_xor(s2, 2);
    s += __shfl_xor(s, 4); s2 += __shfl_xor(s2, 4);
    if (q == 0) {
      const float mean = s * 0.0078125f;
      const float var = s2 * 0.0078125f - mean * mean;
      mu[rw] = mean;
      rs[rw] = rsqrtf(var + 1e-5f);
    }
  }
  __syncthreads();

  // ---- epilogue: coalesced E_new store + coalesced scatter atomics ----
  float* eob = out + (size_t)MF * DD;
  for (int i = 0; i < 16; ++i) {
    const int row = 4 * i + rb;  // wave-uniform
    const float o = (M[row * 132 + colc] - mu[row]) * rs[row] * gec + bec;
    eob[(size_t)(eg0 + row) * DD + colc] = o;
    if (validf[row] != 0.f) {
      atomicAdd(out + (size_t)f1s[row] * DD + colc, o);
      atomicAdd(out + (size_t)f2s[row] * DD + colc, o);
    }
  }
}

// ---------------- Face kernel: 64 faces/block, 8 waves, 2 blocks/CU ----------------
// LDS pool (68608 B):
//   X  u16 [64] pitch 264 @0      (33792)  [F | msg] bf16
//   G  u16 [64] pitch 132 @0               gate bf16 (aliases X)
//   H  u16 [64] pitch 132 @33792  (16896)  hidden bf16
//   U  f32 [64] pitch 132 @33792  (33792)  update fp32 -> u fp32 (aliases H)
//   aux @67584: fmv[64] rv[64] mu[64] rs[64]
__global__ __launch_bounds__(512, 4) void k_face(
    const float* __restrict__ Ffeat, const int* __restrict__ fmask,
    const unsigned short* __restrict__ W1f, const float* __restrict__ b1,
    const unsigned short* __restrict__ W2f, const float* __restrict__ b2,
    const unsigned short* __restrict__ Wgf, const float* __restrict__ bg,
    const float* __restrict__ gf, const float* __restrict__ bef,
    float* __restrict__ out, const float* __restrict__ Fcnt) {
  __shared__ __align__(16) unsigned char pool[68608];
  unsigned short* X = (unsigned short*)pool;              // pitch 264
  unsigned short* G = (unsigned short*)pool;              // pitch 132
  unsigned short* H = (unsigned short*)(pool + 33792);    // pitch 132
  float*          U = (float*)(pool + 33792);             // pitch 132
  float* fmv = (float*)(pool + 67584);
  float* rv  = (float*)(pool + 67840);
  float* mu  = (float*)(pool + 68096);
  float* rs  = (float*)(pool + 68352);

  const int t = threadIdx.x;
  const int lane = t & 63;
  const int w = t >> 6;
  const int l15 = lane & 15;
  const int l4 = lane >> 4;
  const int fg0 = blockIdx.x * 64;

  if (t < 64) {
    fmv[t] = fmask[fg0 + t] ? 1.0f : 0.0f;
    rv[t] = 1.0f / (Fcnt[fg0 + t] + 1e-8f);
  }
  __syncthreads();

  // ---- staging: X = [F | msg*rinv] ----
  for (int k = 0; k < 2; ++k) {
    const int c = k * 512 + t, row = c >> 4, j = c & 15;
    const float* sf = Ffeat + (size_t)(fg0 + row) * DD + j * 8;
    *(bf16x8*)(X + row * 264 + j * 8) =
        pack8(*(const float4*)sf, *(const float4*)(sf + 4));
  }
  for (int k = 0; k < 2; ++k) {
    const int c = k * 512 + t, row = c >> 4, j = c & 15;
    const float* sm = out + (size_t)(fg0 + row) * DD + j * 8;  // accumulated msgs
    const float ri = rv[row];
    float4 m0 = *(const float4*)sm, m1 = *(const float4*)(sm + 4);
    m0.x *= ri; m0.y *= ri; m0.z *= ri; m0.w *= ri;
    m1.x *= ri; m1.y *= ri; m1.z *= ri; m1.w *= ri;
    *(bf16x8*)(X + row * 264 + 128 + j * 8) = pack8(m0, m1);
  }
  __syncthreads();

  // ---- GEMM ef1: (64x256)@(256x128) -> GELU -> H, wave w -> cols [16w,16w+16) ----
  {
    f32x4 acc[4] = {};
    for (int ks = 0; ks < 8; ++ks) {
      const int kb = ks * 32 + (l4 << 2);
      bf16x8 a[4];
      for (int r = 0; r < 4; ++r) a[r] = ld_ab(X + (r * 16 + l15) * 264 + kb);
      bf16x8 bfr = *(const bf16x8*)(W1f + (((w * 8 + ks) << 6) + lane) * 8);
      for (int r = 0; r < 4; ++r) acc[r] = MFMA16(a[r], bfr, acc[r]);
    }
    const int col = (w << 4) + l15;
    const float bias = b1[col];
    for (int r = 0; r < 4; ++r)
      for (int ri = 0; ri < 4; ++ri) {
        const int rw = r * 16 + (l4 << 2) + ri;
        H[rw * 132 + col] = f2bf(gelu_exact(acc[r][ri] + bias));
      }
  }
  __syncthreads();

  // ---- GEMM ef2: (64x128)@(128x128) -> U fp32 ----
  {
    f32x4 acc2[4] = {};
    for (int ks = 0; ks < 4; ++ks) {
      const int kb = ks * 32 + (l4 << 2);
      bf16x8 a[4];
      for (int r = 0; r < 4; ++r) a[r] = ld_ab(H + (r * 16 + l15) * 132 + kb);
      bf16x8 bfr = *(const bf16x8*)(W2f + (((w * 4 + ks) << 6) + lane) * 8);
      for (int r = 0; r < 4; ++r) acc2[r] = MFMA16(a[r], bfr, acc2[r]);
    }
    __syncthreads();  // H fully read; U may overwrite it
    const int col = (w << 4) + l15;
    const float bias = b2[col];
    for (int r = 0; r < 4; ++r)
      for (int ri = 0; ri < 4; ++ri) {
        const int rw = r * 16 + (l4 << 2) + ri;
        U[rw * 132 + col] = acc2[r][ri] + bias;
      }
  }
  __syncthreads();

  // ---- GEMM gf: [F | update](64x256)@(256x128) ----
  {
    f32x4 acc3[4] = {};
    for (int ks = 0; ks < 8; ++ks) {
      bf16x8 a[4];
      if (ks < 4) {
        const int kb = ks * 32 + (l4 << 2);
        for (int r = 0; r < 4; ++r) a[r] = ld_ab(X + (r * 16 + l15) * 264 + kb);
      } else {
        const int kb = (ks - 4) * 32 + (l4 << 2);
        for (int r = 0; r < 4; ++r) {
          const float* p = U + (r * 16 + l15) * 132 + kb;
          union { unsigned short us[8]; bf16x8 v; } u;
          for (int j = 0; j < 4; ++j) { u.us[j] = f2bf(p[j]); u.us[4 + j] = f2bf(p[16 + j]); }
          a[r] = u.v;
        }
      }
      bf16x8 bfr = *(const bf16x8*)(Wgf + (((w * 8 + ks) << 6) + lane) * 8);
      for (int r = 0; r < 4; ++r) acc3[r] = MFMA16(a[r], bfr, acc3[r]);
    }
    __syncthreads();  // X fully read; G may overwrite it
    const int col = (w << 4) + l15;
    const float bias = bg[col];
    for (int r = 0; r < 4; ++r)
      for (int ri = 0; ri < 4; ++ri) {
        const int rw = r * 16 + (l4 << 2) + ri;
        G[rw * 132 + col] = f2bf(sigmoidf_(acc3[r][ri] + bias));
      }
  }
  __syncthreads();

  // ---- u = F + gate*update*mask (coalesced) ----
  const int colc = t & 127;
  const int rb = t >> 7;
  const float gfc = gf[colc], bfc = bef[colc];
  for (int i = 0; i < 16; ++i) {
    const int row = 4 * i + rb;
    const float fv = Ffeat[(size_t)(fg0 + row) * DD + colc];
    const float gv = bf2f(G[row * 132 + colc]);
    const float uv = U[row * 132 + colc];
    U[row * 132 + colc] = fv + gv * uv * fmv[row];
  }
  __syncthreads();

  {  // ---- LN stats: 8 threads/row ----
    const int rw = t >> 3, q = t & 7;
    const float* ur = U + rw * 132 + q * 16;
    float s = 0.f, s2 = 0.f;
    for (int j = 0; j < 4; ++j) {
      float4 v = *(const float4*)(ur + 4 * j);
      s += v.x + v.y + v.z + v.w;
      s2 += v.x * v.x + v.y * v.y + v.z * v.z + v.w * v.w;
    }
    s += __shfl_xor(s, 1); s2 += __shfl_xor(s2, 1);
    s += __shfl_xor(s, 2); s2 += __shfl_xor(s2, 2);
    s += __shfl_xor(s, 4); s2 += __shfl_xor(s2, 4);
    if (q == 0) {
      const float mean = s * 0.0078125f;
      const float var = s2 * 0.0078125f - mean * mean;
      mu[rw] = mean;
      rs[rw] = rsqrtf(var + 1e-5f);
    }
  }
  __syncthreads();

  // ---- epilogue: coalesced F_new store (overwrites msg accumulator) ----
  for (int i = 0; i < 16; ++i) {
    const int row = 4 * i + rb;
    const float o = (U[row * 132 + colc] - mu[row]) * rs[row] * gfc + bfc;
    out[(size_t)(fg0 + row) * DD + colc] = o;
  }
}

extern "C" void kernel_launch(void* const* d_in, const int* in_sizes, int n_in,
                              void* d_out, int out_size, void* d_ws, size_t ws_size,
                              hipStream_t stream) {
  const float* Ffeat = (const float*)d_in[0];
  const float* Efeat = (const float*)d_in[1];
  const int* e2f = (const int*)d_in[2];
  const int* fmask = (const int*)d_in[3];
  const int* emask = (const int*)d_in[4];
  const float* w_fe1 = (const float*)d_in[5];
  const float* b_fe1 = (const float*)d_in[6];
  const float* w_fe2 = (const float*)d_in[7];
  const float* b_fe2 = (const float*)d_in[8];
  const float* w_ge = (const float*)d_in[9];
  const float* b_ge = (const float*)d_in[10];
  const float* g_e = (const float*)d_in[11];
  const float* beta_e = (const float*)d_in[12];
  const float* w_ef1 = (const float*)d_in[13];
  const float* b_ef1 = (const float*)d_in[14];
  const float* w_ef2 = (const float*)d_in[15];
  const float* b_ef2 = (const float*)d_in[16];
  const float* w_gf = (const float*)d_in[17];
  const float* b_gf = (const float*)d_in[18];
  const float* g_f = (const float*)d_in[19];
  const float* beta_f = (const float*)d_in[20];

  float* out = (float*)d_out;
  float* Fcnt = (float*)d_ws;
  unsigned short* wbase = (unsigned short*)((char*)d_ws + (size_t)MF * sizeof(float));
  unsigned short* W1f = wbase;             // 384*256
  unsigned short* W2f = W1f + 98304;       // 256*128
  unsigned short* Wgf = W2f + 32768;       // 256*128
  unsigned short* Wef1 = Wgf + 32768;      // 256*128
  unsigned short* Wef2 = Wef1 + 32768;     // 128*128
  unsigned short* Wgff = Wef2 + 16384;     // 256*128

  // F region of d_out doubles as the face-message accumulator; zero it + counts.
  hipMemsetAsync(out, 0, (size_t)MF * DD * sizeof(float), stream);
  hipMemsetAsync(Fcnt, 0, (size_t)MF * sizeof(float), stream);

  k_pack<<<(98304 + 255) / 256, 256, 0, stream>>>(w_fe1, W1f, 384, 256);
  k_pack<<<(32768 + 255) / 256, 256, 0, stream>>>(w_fe2, W2f, 256, 128);
  k_pack<<<(32768 + 255) / 256, 256, 0, stream>>>(w_ge, Wgf, 256, 128);
  k_pack<<<(32768 + 255) / 256, 256, 0, stream>>>(w_ef1, Wef1, 256, 128);
  k_pack<<<(16384 + 255) / 256, 256, 0, stream>>>(w_ef2, Wef2, 128, 128);
  k_pack<<<(32768 + 255) / 256, 256, 0, stream>>>(w_gf, Wgff, 256, 128);

  k_edge<<<ME / 64, 512, 0, stream>>>(Efeat, Ffeat, e2f, emask, W1f, b_fe1, W2f, b_fe2,
                                      Wgf, b_ge, g_e, beta_e, out, Fcnt);
  k_face<<<MF / 64, 512, 0, stream>>>(Ffeat, fmask, Wef1, b_ef1, Wef2, b_ef2,
                                      Wgff, b_gf, g_f, beta_f, out, Fcnt);
}